// Round 1
// baseline (648.360 us; speedup 1.0000x reference)
//
#include <hip/hip_runtime.h>
#include <cfloat>
#include <math.h>

// Problem constants
#define NTOK 5120   // 4096 full-res tokens + 1024 pooled tokens
#define NFULL 4096
#define CDIM 512
#define VDIM 4096
#define NSEG 16     // argmax segments over V

// ---------------- build token matrix X (NTOK x 512) ----------------
// tok < 4096: full-res  X[tok][c] = z[b][c][t],  b=tok/1024, t=tok%1024
// tok >=4096: pooled    X[tok][c] = mean4(z[b][c][4tq..4tq+3])
__global__ void build_x_k(const float* __restrict__ z, float* __restrict__ X) {
    int idx = blockIdx.x * 256 + threadIdx.x;   // NTOK*512 threads
    int tok = idx >> 9, c = idx & 511;
    float v;
    if (tok < NFULL) {
        int b = tok >> 10, t = tok & 1023;
        v = z[((b << 9) + c) * 1024 + t];
    } else {
        int i = tok - NFULL;
        int b = i >> 8, tq = i & 255;
        const float* zp = z + ((b << 9) + c) * 1024 + (tq << 2);
        v = 0.25f * (zp[0] + zp[1] + zp[2] + zp[3]);
    }
    X[idx] = v;
}

// ---------------- fp32 SGEMM: C[Mx512] = A[Mx512] @ B[512x512] + bias ----
// 128x128 tile, BK=16, 8x8 microtile split as 2x2 blocks of 4x4 (2-way LDS)
__global__ __launch_bounds__(256) void gemm_bias_k(const float* __restrict__ A,
                                                   const float* __restrict__ Bm,
                                                   const float* __restrict__ bias,
                                                   float* __restrict__ Cm) {
    __shared__ float As[16][132];
    __shared__ float Bs[16][132];
    int tid = threadIdx.x;
    int tx = tid & 15, ty = tid >> 4;
    int mBase = blockIdx.x * 128;
    int nBase = blockIdx.y * 128;

    int lrow = tid >> 1;            // 0..127 (A row in tile)
    int k8   = (tid & 1) << 3;      // 0 or 8
    const float* Aload = A + (mBase + lrow) * 512 + k8;
    int bkrow = tid >> 4;           // 0..15 (k row of B tile)
    int bn8   = (tid & 15) << 3;    // 0..120
    const float* Bload = Bm + bkrow * 512 + nBase + bn8;

    float acc[8][8] = {};
    for (int kt = 0; kt < 32; ++kt) {
        float4 a0 = *(const float4*)(Aload + kt * 16);
        float4 a1 = *(const float4*)(Aload + kt * 16 + 4);
        float4 b0 = *(const float4*)(Bload + kt * 16 * 512);
        float4 b1 = *(const float4*)(Bload + kt * 16 * 512 + 4);
        __syncthreads();
        As[k8 + 0][lrow] = a0.x; As[k8 + 1][lrow] = a0.y;
        As[k8 + 2][lrow] = a0.z; As[k8 + 3][lrow] = a0.w;
        As[k8 + 4][lrow] = a1.x; As[k8 + 5][lrow] = a1.y;
        As[k8 + 6][lrow] = a1.z; As[k8 + 7][lrow] = a1.w;
        *(float4*)&Bs[bkrow][bn8]     = b0;
        *(float4*)&Bs[bkrow][bn8 + 4] = b1;
        __syncthreads();
        #pragma unroll
        for (int kk = 0; kk < 16; ++kk) {
            float4 av0 = *(const float4*)&As[kk][(ty << 2)];
            float4 av1 = *(const float4*)&As[kk][64 + (ty << 2)];
            float4 bv0 = *(const float4*)&Bs[kk][(tx << 2)];
            float4 bv1 = *(const float4*)&Bs[kk][64 + (tx << 2)];
            float a[8] = {av0.x, av0.y, av0.z, av0.w, av1.x, av1.y, av1.z, av1.w};
            float b[8] = {bv0.x, bv0.y, bv0.z, bv0.w, bv1.x, bv1.y, bv1.z, bv1.w};
            #pragma unroll
            for (int i = 0; i < 8; ++i)
                #pragma unroll
                for (int j = 0; j < 8; ++j)
                    acc[i][j] = fmaf(a[i], b[j], acc[i][j]);
        }
    }
    #pragma unroll
    for (int ih = 0; ih < 2; ++ih)
        #pragma unroll
        for (int i = 0; i < 4; ++i) {
            int row = mBase + ih * 64 + (ty << 2) + i;
            #pragma unroll
            for (int jh = 0; jh < 2; ++jh) {
                int col = nBase + jh * 64 + (tx << 2);
                float4 r;
                r.x = acc[ih * 4 + i][jh * 4 + 0] + bias[col + 0];
                r.y = acc[ih * 4 + i][jh * 4 + 1] + bias[col + 1];
                r.z = acc[ih * 4 + i][jh * 4 + 2] + bias[col + 2];
                r.w = acc[ih * 4 + i][jh * 4 + 3] + bias[col + 3];
                *(float4*)&Cm[row * 512 + col] = r;
            }
        }
}

// ---------------- head-pool weights: Cp[NTOK x 8] = X @ Wp + bp ----------
__global__ void pool_c_k(const float* __restrict__ X, const float* __restrict__ Wp,
                         const float* __restrict__ bp, float* __restrict__ Cp) {
    int idx = blockIdx.x * 256 + threadIdx.x;   // NTOK*8
    int tok = idx >> 3, h = idx & 7;
    const float* x = X + tok * 512;
    float s = 0.f;
    for (int k = 0; k < 512; ++k) s = fmaf(x[k], Wp[k * 8 + h], s);
    Cp[idx] = s + bp[h];
}

// ---------------- rmsnorm Q per (tok,head), fold c and 1/(sqrtD*sqrtH) ---
__global__ void norm_q_k(float* __restrict__ Q, const float* __restrict__ gq,
                         const float* __restrict__ Cp) {
    int wid = (blockIdx.x << 2) + (threadIdx.x >> 6);
    int lane = threadIdx.x & 63;
    int tok = wid >> 3, h = wid & 7;
    int off = tok * 512 + (h << 6) + lane;
    float v = Q[off];
    float s = v * v;
    #pragma unroll
    for (int o = 32; o > 0; o >>= 1) s += __shfl_xor(s, o);
    float scale = rsqrtf(s * (1.0f / 64.0f) + 1e-5f);
    float cc = Cp[tok * 8 + h] * 0.04419417382415922f;  // 1/(8*sqrt(8))
    Q[off] = v * scale * gq[lane] * cc;
}

__global__ void norm_k_k(float* __restrict__ K, const float* __restrict__ gk) {
    int wid = (blockIdx.x << 2) + (threadIdx.x >> 6);
    int lane = threadIdx.x & 63;
    int off = wid * 64 + lane;   // (n*8+h)*64 + d  == n*512 + h*64 + d
    float v = K[off];
    float s = v * v;
    #pragma unroll
    for (int o = 32; o > 0; o >>= 1) s += __shfl_xor(s, o);
    float scale = rsqrtf(s * (1.0f / 64.0f) + 1e-5f);
    K[off] = v * scale * gk[lane];
}

// ---------------- fused logits GEMM + per-segment argmax ----------------
// logits[tok][n] = sum_k Qp[tok][k] * Kn[n][k]; track running (max,idx) per row
__global__ __launch_bounds__(256) void logits_argmax_k(const float* __restrict__ Qp,
                                                       const float* __restrict__ Kn,
                                                       float* __restrict__ segval,
                                                       int* __restrict__ segidx) {
    __shared__ float As[16][132];
    __shared__ float Bs[16][132];
    int tid = threadIdx.x;
    int tx = tid & 15, ty = tid >> 4;
    int mBase = blockIdx.x * 128;
    int seg = blockIdx.y;                 // 16 segs * 256 cols
    int segBase = seg * 256;

    int lrow = tid >> 1;
    int k8   = (tid & 1) << 3;
    const float* Aload = Qp + (mBase + lrow) * 512 + k8;

    float best[8]; int bidx[8];
    #pragma unroll
    for (int r = 0; r < 8; ++r) { best[r] = -FLT_MAX; bidx[r] = 0x7fffffff; }

    for (int nc = 0; nc < 2; ++nc) {
        int nBase = segBase + nc * 128;
        const float* Bload = Kn + (nBase + lrow) * 512 + k8;
        float acc[8][8] = {};
        for (int kt = 0; kt < 32; ++kt) {
            float4 a0 = *(const float4*)(Aload + kt * 16);
            float4 a1 = *(const float4*)(Aload + kt * 16 + 4);
            float4 b0 = *(const float4*)(Bload + kt * 16);
            float4 b1 = *(const float4*)(Bload + kt * 16 + 4);
            __syncthreads();
            As[k8 + 0][lrow] = a0.x; As[k8 + 1][lrow] = a0.y;
            As[k8 + 2][lrow] = a0.z; As[k8 + 3][lrow] = a0.w;
            As[k8 + 4][lrow] = a1.x; As[k8 + 5][lrow] = a1.y;
            As[k8 + 6][lrow] = a1.z; As[k8 + 7][lrow] = a1.w;
            Bs[k8 + 0][lrow] = b0.x; Bs[k8 + 1][lrow] = b0.y;
            Bs[k8 + 2][lrow] = b0.z; Bs[k8 + 3][lrow] = b0.w;
            Bs[k8 + 4][lrow] = b1.x; Bs[k8 + 5][lrow] = b1.y;
            Bs[k8 + 6][lrow] = b1.z; Bs[k8 + 7][lrow] = b1.w;
            __syncthreads();
            #pragma unroll
            for (int kk = 0; kk < 16; ++kk) {
                float4 av0 = *(const float4*)&As[kk][(ty << 2)];
                float4 av1 = *(const float4*)&As[kk][64 + (ty << 2)];
                float4 bv0 = *(const float4*)&Bs[kk][(tx << 2)];
                float4 bv1 = *(const float4*)&Bs[kk][64 + (tx << 2)];
                float a[8] = {av0.x, av0.y, av0.z, av0.w, av1.x, av1.y, av1.z, av1.w};
                float b[8] = {bv0.x, bv0.y, bv0.z, bv0.w, bv1.x, bv1.y, bv1.z, bv1.w};
                #pragma unroll
                for (int i = 0; i < 8; ++i)
                    #pragma unroll
                    for (int j = 0; j < 8; ++j)
                        acc[i][j] = fmaf(a[i], b[j], acc[i][j]);
            }
        }
        #pragma unroll
        for (int ih = 0; ih < 2; ++ih)
            #pragma unroll
            for (int i = 0; i < 4; ++i) {
                int r = ih * 4 + i;
                #pragma unroll
                for (int jh = 0; jh < 2; ++jh)
                    #pragma unroll
                    for (int j = 0; j < 4; ++j) {
                        float v = acc[r][jh * 4 + j];
                        int n = nBase + jh * 64 + (tx << 2) + j;
                        if (v > best[r] || (v == best[r] && n < bidx[r])) {
                            best[r] = v; bidx[r] = n;
                        }
                    }
            }
    }
    // reduce across the 16 tx lanes (contiguous lanes share ty within a wave)
    #pragma unroll
    for (int r = 0; r < 8; ++r) {
        float v = best[r]; int ix = bidx[r];
        #pragma unroll
        for (int off = 1; off < 16; off <<= 1) {
            float ov = __shfl_xor(v, off);
            int   oi = __shfl_xor(ix, off);
            if (ov > v || (ov == v && oi < ix)) { v = ov; ix = oi; }
        }
        if (tx == 0) {
            int tok = mBase + ((r >= 4) ? 64 : 0) + (ty << 2) + (r & 3);
            segval[tok * NSEG + seg] = v;
            segidx[tok * NSEG + seg] = ix;
        }
    }
}

// ---------------- merge segments -> argmax code per token ----------------
__global__ void merge_code_k(const float* __restrict__ segval,
                             const int* __restrict__ segidx, int* __restrict__ code) {
    int tok = blockIdx.x * 256 + threadIdx.x;
    if (tok >= NTOK) return;
    float bv = -FLT_MAX; int bi = 0x7fffffff;
    for (int s = 0; s < NSEG; ++s) {
        float v = segval[tok * NSEG + s];
        int  ix = segidx[tok * NSEG + s];
        if (v > bv || (v == bv && ix < bi)) { bv = v; bi = ix; }
    }
    code[tok] = bi;
}

// ---------------- histogram + perplexity --------------------------------
__global__ void zero_counts_k(int* counts) { counts[blockIdx.x * 256 + threadIdx.x] = 0; }

__global__ void hist_k(const int* __restrict__ code, int* __restrict__ counts) {
    int i = blockIdx.x * 256 + threadIdx.x;
    if (i < NFULL) atomicAdd(&counts[code[i]], 1);
}

__global__ void perplexity_k(const int* __restrict__ counts, float* __restrict__ out) {
    __shared__ float red[256];
    float s = 0.f;
    for (int i = threadIdx.x; i < VDIM; i += 256) {
        float p = (float)counts[i] * (1.0f / 4096.0f);
        s += p * logf(p + 1e-7f);
    }
    red[threadIdx.x] = s; __syncthreads();
    for (int st = 128; st > 0; st >>= 1) {
        if (threadIdx.x < st) red[threadIdx.x] += red[threadIdx.x + st];
        __syncthreads();
    }
    if (threadIdx.x == 0) out[0] = expf(-red[0]);
}

// ---------------- z_hat: gather value rows + linear interp x4 ------------
__global__ void zhat_k(const float* __restrict__ Vv, const int* __restrict__ code,
                       float* __restrict__ out) {
    int idx = blockIdx.x * 256 + threadIdx.x;   // 4*512*1024
    int t  = idx & 1023;
    int bc = idx >> 10;
    int b  = bc >> 9, c = bc & 511;
    float pos = (t + 0.5f) * 0.25f - 0.5f;
    pos = fminf(fmaxf(pos, 0.0f), 255.0f);
    float fi = floorf(pos);
    int i0 = (int)fi;
    int i1 = min(i0 + 1, 255);
    float w = pos - fi;
    const int* cb = code + NFULL + (b << 8);
    float v0 = Vv[cb[i0] * 512 + c];
    float v1 = Vv[cb[i1] * 512 + c];
    out[idx] = v0 * (1.0f - w) + v1 * w;
}

extern "C" void kernel_launch(void* const* d_in, const int* in_sizes, int n_in,
                              void* d_out, int out_size, void* d_ws, size_t ws_size,
                              hipStream_t stream) {
    const float* z  = (const float*)d_in[0];
    const float* cb = (const float*)d_in[2];
    const float* Wq = (const float*)d_in[3];
    const float* bq = (const float*)d_in[4];
    const float* Wk = (const float*)d_in[5];
    const float* bk = (const float*)d_in[6];
    const float* Wv = (const float*)d_in[7];
    const float* bv = (const float*)d_in[8];
    const float* Wp = (const float*)d_in[9];
    const float* bp = (const float*)d_in[10];
    const float* gq = (const float*)d_in[11];
    const float* gk = (const float*)d_in[12];
    float* out = (float*)d_out;

    // workspace layout (~38.6 MB)
    float* X      = (float*)d_ws;          // 5120*512
    float* Qb     = X + 5120 * 512;        // 5120*512
    float* Kb     = Qb + 5120 * 512;       // 4096*512
    float* Vb     = Kb + 4096 * 512;       // 4096*512
    float* Cp     = Vb + 4096 * 512;       // 5120*8
    float* segval = Cp + 5120 * 8;         // 5120*16
    int*   segidx = (int*)(segval + 5120 * NSEG);  // 5120*16
    int*   code   = segidx + 5120 * NSEG;  // 5120
    int*   counts = code + 5120;           // 4096

    build_x_k<<<10240, 256, 0, stream>>>(z, X);
    gemm_bias_k<<<dim3(40, 4), 256, 0, stream>>>(X,  Wq, bq, Qb);
    gemm_bias_k<<<dim3(32, 4), 256, 0, stream>>>(cb, Wk, bk, Kb);
    gemm_bias_k<<<dim3(32, 4), 256, 0, stream>>>(cb, Wv, bv, Vb);
    pool_c_k<<<160, 256, 0, stream>>>(X, Wp, bp, Cp);
    norm_q_k<<<10240, 256, 0, stream>>>(Qb, gq, Cp);
    norm_k_k<<<8192, 256, 0, stream>>>(Kb, gk);
    logits_argmax_k<<<dim3(40, NSEG), 256, 0, stream>>>(Qb, Kb, segval, segidx);
    merge_code_k<<<20, 256, 0, stream>>>(segval, segidx, code);
    zero_counts_k<<<16, 256, 0, stream>>>(counts);
    hist_k<<<16, 256, 0, stream>>>(code, counts);
    perplexity_k<<<1, 256, 0, stream>>>(counts, out + 4 * 512 * 1024);
    zhat_k<<<8192, 256, 0, stream>>>(Vb, code, out);
}

// Round 2
// 343.627 us; speedup vs baseline: 1.8868x; 1.8868x over previous
//
#include <hip/hip_runtime.h>
#include <hip/hip_bf16.h>
#include <cfloat>
#include <math.h>

#define NFULL 4096
#define NPOOL 1024
#define NTOK  5120
#define VDIM  4096
#define NSEG  64

typedef __attribute__((ext_vector_type(8))) short short8;   // 8 bf16 (4 VGPR)
typedef __attribute__((ext_vector_type(4))) float f4;       // MFMA acc

#define MFMA16(a,b,c) __builtin_amdgcn_mfma_f32_16x16x32_bf16((a),(b),(c),0,0,0)

// ---------------- build token matrix X (NTOK x 512) + bf16 copy of full rows
__global__ void build_x_k(const float* __restrict__ z, float* __restrict__ X,
                          __hip_bfloat16* __restrict__ Xh) {
    int idx = blockIdx.x * 256 + threadIdx.x;   // NTOK*512
    int tok = idx >> 9, c = idx & 511;
    float v;
    if (tok < NFULL) {
        int b = tok >> 10, t = tok & 1023;
        v = z[((b << 9) + c) * 1024 + t];
        Xh[idx] = __float2bfloat16(v);
    } else {
        int i = tok - NFULL;
        int b = i >> 8, tq = i & 255;
        const float* zp = z + ((b << 9) + c) * 1024 + (tq << 2);
        v = 0.25f * (zp[0] + zp[1] + zp[2] + zp[3]);
    }
    X[idx] = v;
}

__global__ void cast_bf16_k(const float* __restrict__ s, __hip_bfloat16* __restrict__ d) {
    int i = blockIdx.x * 256 + threadIdx.x;
    d[i] = __float2bfloat16(s[i]);
}

// ---------------- transpose+cast 512x512: W[k][n] fp32 -> WT[n][k] bf16 ----
__global__ void transpose_cast_k(const float* __restrict__ W, __hip_bfloat16* __restrict__ WT) {
    __shared__ float t[32][33];
    int bk = blockIdx.x * 32, bn = blockIdx.y * 32;
    int lx = threadIdx.x & 31, ly = threadIdx.x >> 5;   // ly 0..7
    #pragma unroll
    for (int i = 0; i < 4; ++i) {
        int r = ly * 4 + i;
        t[r][lx] = W[(bk + r) * 512 + bn + lx];
    }
    __syncthreads();
    #pragma unroll
    for (int i = 0; i < 4; ++i) {
        int r = ly * 4 + i;   // n-local
        WT[(bn + r) * 512 + bk + lx] = __float2bfloat16(t[lx][r]);
    }
}

// ---------------- head-pool weights: Cp[NTOK x 8] = X @ Wp + bp, Wp in LDS -
__global__ void pool_c_k(const float* __restrict__ X, const float* __restrict__ Wp,
                         const float* __restrict__ bp, float* __restrict__ Cp) {
    __shared__ float W[4096];
    for (int i = threadIdx.x; i < 4096; i += 256) W[i] = Wp[i];
    __syncthreads();
    int tokBase = blockIdx.x * 32;
    int tl = threadIdx.x >> 3, h = threadIdx.x & 7;
    const float* x = X + (tokBase + tl) * 512;
    float s = 0.f;
    for (int k4 = 0; k4 < 128; ++k4) {
        float4 xv = *(const float4*)(x + k4 * 4);
        s = fmaf(xv.x, W[(k4 * 4 + 0) * 8 + h], s);
        s = fmaf(xv.y, W[(k4 * 4 + 1) * 8 + h], s);
        s = fmaf(xv.z, W[(k4 * 4 + 2) * 8 + h], s);
        s = fmaf(xv.w, W[(k4 * 4 + 3) * 8 + h], s);
    }
    Cp[(tokBase + tl) * 8 + h] = s + bp[h];
}

// ---------------- fp32 64x64 GEMM + fused rmsnorm epilogue -----------------
// out[M][512] = rmsnorm_per_head(A[M][512] @ B[512][512] + bias) * g [* cc]
// N-tile 64 == head dim, so sum-of-squares closes within one block.
__global__ __launch_bounds__(256) void sgemm64_norm_k(
    const float* __restrict__ A, const float* __restrict__ B,
    const float* __restrict__ bias, const float* __restrict__ g,
    const float* __restrict__ cp,          // nullptr -> cc = 1
    float* __restrict__ outF, __hip_bfloat16* __restrict__ outH) {
    __shared__ float As[16][68];
    __shared__ float Bs[16][68];
    int tid = threadIdx.x;
    int mB = blockIdx.x * 64, h = blockIdx.y, nB = h * 64;
    int ty = tid >> 4, tx = tid & 15;
    int arow = tid >> 2, achk = tid & 3;
    int bkrow = tid >> 4, bchk = (tid & 15) * 4;
    const float* Ap = A + (mB + arow) * 512 + achk * 4;
    const float* Bp = B + bkrow * 512 + nB + bchk;
    float acc[4][4] = {};
    for (int kt = 0; kt < 32; ++kt) {
        float4 a = *(const float4*)(Ap + kt * 16);
        float4 b = *(const float4*)(Bp + kt * 16 * 512);
        __syncthreads();
        As[achk * 4 + 0][arow] = a.x; As[achk * 4 + 1][arow] = a.y;
        As[achk * 4 + 2][arow] = a.z; As[achk * 4 + 3][arow] = a.w;
        *(float4*)&Bs[bkrow][bchk] = b;
        __syncthreads();
        #pragma unroll
        for (int kk = 0; kk < 16; ++kk) {
            float4 av = *(const float4*)&As[kk][ty * 4];
            float4 bv = *(const float4*)&Bs[kk][tx * 4];
            float a4[4] = {av.x, av.y, av.z, av.w};
            float b4[4] = {bv.x, bv.y, bv.z, bv.w};
            #pragma unroll
            for (int i = 0; i < 4; ++i)
                #pragma unroll
                for (int j = 0; j < 4; ++j)
                    acc[i][j] = fmaf(a4[i], b4[j], acc[i][j]);
        }
    }
    float4 b4 = *(const float4*)&bias[nB + tx * 4];
    float4 g4 = *(const float4*)&g[tx * 4];
    float bb[4] = {b4.x, b4.y, b4.z, b4.w};
    float gg[4] = {g4.x, g4.y, g4.z, g4.w};
    #pragma unroll
    for (int i = 0; i < 4; ++i) {
        float vv[4], ss = 0.f;
        #pragma unroll
        for (int j = 0; j < 4; ++j) { vv[j] = acc[i][j] + bb[j]; ss = fmaf(vv[j], vv[j], ss); }
        #pragma unroll
        for (int off = 1; off < 16; off <<= 1) ss += __shfl_xor(ss, off);
        int m = mB + ty * 4 + i;
        float sc = rsqrtf(ss * (1.0f / 64.0f) + 1e-5f);
        if (cp) sc *= cp[m * 8 + h] * 0.04419417382415922f;   // 1/(8*sqrt(8))
        float4 o;
        o.x = vv[0] * sc * gg[0]; o.y = vv[1] * sc * gg[1];
        o.z = vv[2] * sc * gg[2]; o.w = vv[3] * sc * gg[3];
        *(float4*)&outF[m * 512 + nB + tx * 4] = o;
        if (outH) {
            __hip_bfloat16* oh = outH + m * 512 + nB + tx * 4;
            oh[0] = __float2bfloat16(o.x); oh[1] = __float2bfloat16(o.y);
            oh[2] = __float2bfloat16(o.z); oh[3] = __float2bfloat16(o.w);
        }
    }
}

// ---------------- bf16 MFMA 128x128 GEMM core (shared staging layout) ------
// A[M][512] bf16, Bt[N][512] bf16 (n-major). 16x16x32 MFMA, 2x2 waves,
// per-wave 4x4 tiles. LDS rows padded to 40 bf16 for balanced banks.
#define BGEMM_PROLOG()                                                         \
    __shared__ __hip_bfloat16 As[128 * 40];                                    \
    __shared__ __hip_bfloat16 Bs[128 * 40];                                    \
    int tid = threadIdx.x;                                                     \
    int mB = blockIdx.x * 128, nB = blockIdx.y * 128;                          \
    int lane = tid & 63, w = tid >> 6, wy = w >> 1, wx = w & 1;                \
    int lm = lane & 15, quad = lane >> 4;                                      \
    int r0 = tid >> 2, c0 = tid & 3;                                           \
    int r1 = (tid + 256) >> 2;                                                 \
    const __hip_bfloat16* Ag0 = AM + (mB + r0) * 512 + c0 * 8;                 \
    const __hip_bfloat16* Ag1 = AM + (mB + r1) * 512 + c0 * 8;                 \
    const __hip_bfloat16* Bg0 = Bt + (nB + r0) * 512 + c0 * 8;                 \
    const __hip_bfloat16* Bg1 = Bt + (nB + r1) * 512 + c0 * 8;                 \
    __hip_bfloat16* Aw0 = As + r0 * 40 + c0 * 8;                               \
    __hip_bfloat16* Aw1 = As + r1 * 40 + c0 * 8;                               \
    __hip_bfloat16* Bw0 = Bs + r0 * 40 + c0 * 8;                               \
    __hip_bfloat16* Bw1 = Bs + r1 * 40 + c0 * 8;                               \
    f4 acc[4][4];                                                              \
    _Pragma("unroll") for (int i = 0; i < 4; ++i)                              \
        _Pragma("unroll") for (int j = 0; j < 4; ++j)                          \
            acc[i][j] = f4{0.f, 0.f, 0.f, 0.f};                                \
    for (int kt = 0; kt < 16; ++kt) {                                          \
        short8 a0 = *(const short8*)(Ag0 + kt * 32);                           \
        short8 a1 = *(const short8*)(Ag1 + kt * 32);                           \
        short8 b0 = *(const short8*)(Bg0 + kt * 32);                           \
        short8 b1 = *(const short8*)(Bg1 + kt * 32);                           \
        __syncthreads();                                                       \
        *(short8*)Aw0 = a0; *(short8*)Aw1 = a1;                                \
        *(short8*)Bw0 = b0; *(short8*)Bw1 = b1;                                \
        __syncthreads();                                                       \
        short8 aF[4], bF[4];                                                   \
        _Pragma("unroll") for (int mt = 0; mt < 4; ++mt)                       \
            aF[mt] = *(const short8*)(As + (wy * 64 + mt * 16 + lm) * 40 + quad * 8); \
        _Pragma("unroll") for (int nt = 0; nt < 4; ++nt)                       \
            bF[nt] = *(const short8*)(Bs + (wx * 64 + nt * 16 + lm) * 40 + quad * 8); \
        _Pragma("unroll") for (int mt = 0; mt < 4; ++mt)                       \
            _Pragma("unroll") for (int nt = 0; nt < 4; ++nt)                   \
                acc[mt][nt] = MFMA16(aF[mt], bF[nt], acc[mt][nt]);             \
    }

// V projection: C fp32 = A@Bt^T + bias
__global__ __launch_bounds__(256) void bgemm_bias_k(
    const __hip_bfloat16* __restrict__ AM, const __hip_bfloat16* __restrict__ Bt,
    const float* __restrict__ bias, float* __restrict__ C) {
    BGEMM_PROLOG()
    float bb[4];
    #pragma unroll
    for (int nt = 0; nt < 4; ++nt) bb[nt] = bias[nB + wx * 64 + nt * 16 + lm];
    #pragma unroll
    for (int mt = 0; mt < 4; ++mt)
        #pragma unroll
        for (int reg = 0; reg < 4; ++reg) {
            int m = mB + wy * 64 + mt * 16 + quad * 4 + reg;
            #pragma unroll
            for (int nt = 0; nt < 4; ++nt)
                C[m * 512 + nB + wx * 64 + nt * 16 + lm] = acc[mt][nt][reg] + bb[nt];
        }
}

// Q projection with fused rmsnorm + c-fold -> bf16 out (full-res path)
__global__ __launch_bounds__(256) void bgemm_qnorm_k(
    const __hip_bfloat16* __restrict__ AM, const __hip_bfloat16* __restrict__ Bt,
    const float* __restrict__ bias, const float* __restrict__ gq,
    const float* __restrict__ cp, __hip_bfloat16* __restrict__ outH) {
    BGEMM_PROLOG()
    int h = blockIdx.y * 2 + wx;            // wave's 64 cols == one head
    float bb[4], gg[4];
    #pragma unroll
    for (int nt = 0; nt < 4; ++nt) {
        bb[nt] = bias[h * 64 + nt * 16 + lm];
        gg[nt] = gq[nt * 16 + lm];
    }
    #pragma unroll
    for (int mt = 0; mt < 4; ++mt)
        #pragma unroll
        for (int reg = 0; reg < 4; ++reg) {
            int tok = mB + wy * 64 + mt * 16 + quad * 4 + reg;
            float vv[4], ss = 0.f;
            #pragma unroll
            for (int nt = 0; nt < 4; ++nt) { vv[nt] = acc[mt][nt][reg] + bb[nt]; ss = fmaf(vv[nt], vv[nt], ss); }
            #pragma unroll
            for (int off = 1; off < 16; off <<= 1) ss += __shfl_xor(ss, off);
            float sc = rsqrtf(ss * (1.0f / 64.0f) + 1e-5f) * cp[tok * 8 + h] * 0.04419417382415922f;
            #pragma unroll
            for (int nt = 0; nt < 4; ++nt)
                outH[tok * 512 + h * 64 + nt * 16 + lm] = __float2bfloat16(vv[nt] * sc * gg[nt]);
        }
}

// Full-res logits + fused argmax (perplexity path, bf16-tolerant)
__global__ __launch_bounds__(256) void logits_full_k(
    const __hip_bfloat16* __restrict__ AM, const __hip_bfloat16* __restrict__ Bt,
    float* __restrict__ segval, int* __restrict__ segidx) {
    BGEMM_PROLOG()
    int seg = blockIdx.y * 2 + wx;
    #pragma unroll
    for (int mt = 0; mt < 4; ++mt)
        #pragma unroll
        for (int reg = 0; reg < 4; ++reg) {
            float bv = -FLT_MAX; int bi = 0x7fffffff;
            #pragma unroll
            for (int nt = 0; nt < 4; ++nt) {
                float v = acc[mt][nt][reg];
                int n = nB + wx * 64 + nt * 16 + lm;
                if (v > bv) { bv = v; bi = n; }
            }
            #pragma unroll
            for (int off = 1; off < 16; off <<= 1) {
                float ov = __shfl_xor(bv, off);
                int oi = __shfl_xor(bi, off);
                if (ov > bv || (ov == bv && oi < bi)) { bv = ov; bi = oi; }
            }
            if (lm == 0) {
                int tok = mB + wy * 64 + mt * 16 + quad * 4 + reg;
                segval[tok * NSEG + seg] = bv;
                segidx[tok * NSEG + seg] = bi;
            }
        }
}

// ---------------- pooled logits fp32 (exact path) + fused argmax -----------
// 64x128 tile: A = Qpool [1024][512], B = Kn [4096][512] (n-major)
__global__ __launch_bounds__(256) void logits_pool_k(
    const float* __restrict__ Qp, const float* __restrict__ Kn,
    float* __restrict__ segval, int* __restrict__ segidx) {
    __shared__ float As[16][68];
    __shared__ float Bs[16][132];
    int tid = threadIdx.x;
    int mB = blockIdx.x * 64, nB = blockIdx.y * 128;
    int ty = tid >> 4, tx = tid & 15;
    int arow = tid >> 2, achk = tid & 3;
    const float* Ap = Qp + (mB + arow) * 512 + achk * 4;
    const float* Bp0 = Kn + (nB + arow) * 512 + achk * 4;
    const float* Bp1 = Kn + (nB + arow + 64) * 512 + achk * 4;
    float acc[4][8] = {};
    for (int kt = 0; kt < 32; ++kt) {
        float4 a  = *(const float4*)(Ap + kt * 16);
        float4 b0 = *(const float4*)(Bp0 + kt * 16);
        float4 b1 = *(const float4*)(Bp1 + kt * 16);
        __syncthreads();
        As[achk * 4 + 0][arow] = a.x;  As[achk * 4 + 1][arow] = a.y;
        As[achk * 4 + 2][arow] = a.z;  As[achk * 4 + 3][arow] = a.w;
        Bs[achk * 4 + 0][arow] = b0.x; Bs[achk * 4 + 1][arow] = b0.y;
        Bs[achk * 4 + 2][arow] = b0.z; Bs[achk * 4 + 3][arow] = b0.w;
        Bs[achk * 4 + 0][arow + 64] = b1.x; Bs[achk * 4 + 1][arow + 64] = b1.y;
        Bs[achk * 4 + 2][arow + 64] = b1.z; Bs[achk * 4 + 3][arow + 64] = b1.w;
        __syncthreads();
        #pragma unroll
        for (int kk = 0; kk < 16; ++kk) {
            float4 av  = *(const float4*)&As[kk][ty * 4];
            float4 bv0 = *(const float4*)&Bs[kk][tx * 4];
            float4 bv1 = *(const float4*)&Bs[kk][64 + tx * 4];
            float a4[4] = {av.x, av.y, av.z, av.w};
            float b8[8] = {bv0.x, bv0.y, bv0.z, bv0.w, bv1.x, bv1.y, bv1.z, bv1.w};
            #pragma unroll
            for (int i = 0; i < 4; ++i)
                #pragma unroll
                for (int j = 0; j < 8; ++j)
                    acc[i][j] = fmaf(a4[i], b8[j], acc[i][j]);
        }
    }
    #pragma unroll
    for (int i = 0; i < 4; ++i) {
        float bv = -FLT_MAX; int bi = 0x7fffffff;
        #pragma unroll
        for (int j = 0; j < 4; ++j) {
            float v = acc[i][j]; int n = nB + tx * 4 + j;
            if (v > bv) { bv = v; bi = n; }
        }
        #pragma unroll
        for (int j = 0; j < 4; ++j) {
            float v = acc[i][4 + j]; int n = nB + 64 + tx * 4 + j;
            if (v > bv) { bv = v; bi = n; }
        }
        #pragma unroll
        for (int off = 1; off < 16; off <<= 1) {
            float ov = __shfl_xor(bv, off);
            int oi = __shfl_xor(bi, off);
            if (ov > bv || (ov == bv && oi < bi)) { bv = ov; bi = oi; }
        }
        if (tx == 0) {
            int tok = NFULL + mB + ty * 4 + i;
            segval[tok * NSEG + blockIdx.y] = bv;
            segidx[tok * NSEG + blockIdx.y] = bi;
        }
    }
}

// ---------------- merge segments -> code per token -------------------------
__global__ void merge_code_k(const float* __restrict__ segval,
                             const int* __restrict__ segidx, int* __restrict__ code) {
    int tok = blockIdx.x * 256 + threadIdx.x;
    if (tok >= NTOK) return;
    int ns = (tok < NFULL) ? 64 : 32;
    float bv = -FLT_MAX; int bi = 0x7fffffff;
    for (int s = 0; s < ns; ++s) {
        float v = segval[tok * NSEG + s];
        int ix = segidx[tok * NSEG + s];
        if (v > bv || (v == bv && ix < bi)) { bv = v; bi = ix; }
    }
    code[tok] = bi;
}

// ---------------- histogram + perplexity -----------------------------------
__global__ void zero_counts_k(int* counts) { counts[blockIdx.x * 256 + threadIdx.x] = 0; }

__global__ void hist_k(const int* __restrict__ code, int* __restrict__ counts) {
    int i = blockIdx.x * 256 + threadIdx.x;
    if (i < NFULL) atomicAdd(&counts[code[i]], 1);
}

__global__ void perplexity_k(const int* __restrict__ counts, float* __restrict__ out) {
    __shared__ float red[256];
    float s = 0.f;
    for (int i = threadIdx.x; i < VDIM; i += 256) {
        float p = (float)counts[i] * (1.0f / 4096.0f);
        s += p * logf(p + 1e-7f);
    }
    red[threadIdx.x] = s; __syncthreads();
    for (int st = 128; st > 0; st >>= 1) {
        if (threadIdx.x < st) red[threadIdx.x] += red[threadIdx.x + st];
        __syncthreads();
    }
    if (threadIdx.x == 0) out[0] = expf(-red[0]);
}

// ---------------- z_hat: gather value rows + linear interp x4 ---------------
__global__ void zhat_k(const float* __restrict__ Vv, const int* __restrict__ code,
                       float* __restrict__ out) {
    int idx = blockIdx.x * 256 + threadIdx.x;   // 4*512*1024
    int t = idx & 1023;
    int bc = idx >> 10;
    int b = bc >> 9, c = bc & 511;
    float pos = (t + 0.5f) * 0.25f - 0.5f;
    pos = fminf(fmaxf(pos, 0.0f), 255.0f);
    float fi = floorf(pos);
    int i0 = (int)fi;
    int i1 = min(i0 + 1, 255);
    float wgt = pos - fi;
    const int* cp = code + NFULL + (b << 8);
    float v0 = Vv[cp[i0] * 512 + c];
    float v1 = Vv[cp[i1] * 512 + c];
    out[idx] = v0 * (1.0f - wgt) + v1 * wgt;
}

extern "C" void kernel_launch(void* const* d_in, const int* in_sizes, int n_in,
                              void* d_out, int out_size, void* d_ws, size_t ws_size,
                              hipStream_t stream) {
    const float* z   = (const float*)d_in[0];
    const float* cbk = (const float*)d_in[2];
    const float* Wq  = (const float*)d_in[3];
    const float* bq  = (const float*)d_in[4];
    const float* Wk  = (const float*)d_in[5];
    const float* bk  = (const float*)d_in[6];
    const float* Wv  = (const float*)d_in[7];
    const float* bv  = (const float*)d_in[8];
    const float* Wp  = (const float*)d_in[9];
    const float* bp  = (const float*)d_in[10];
    const float* gq  = (const float*)d_in[11];
    const float* gk  = (const float*)d_in[12];
    float* out = (float*)d_out;

    // workspace layout (~46 MB)
    float* X      = (float*)d_ws;                    // 5120*512
    float* Qpool  = X + 5120 * 512;                  // 1024*512 (normed fp32)
    float* Kn     = Qpool + 1024 * 512;              // 4096*512 (normed fp32)
    float* Vb     = Kn + 4096 * 512;                 // 4096*512
    float* Cp     = Vb + 4096 * 512;                 // 5120*8
    float* segval = Cp + 5120 * 8;                   // 5120*64
    int*   segidx = (int*)(segval + 5120 * NSEG);    // 5120*64
    int*   code   = segidx + 5120 * NSEG;            // 5120
    int*   counts = code + 5120;                     // 4096
    __hip_bfloat16* Xh  = (__hip_bfloat16*)(counts + 4096);  // 4096*512
    __hip_bfloat16* Qh  = Xh + 4096 * 512;
    __hip_bfloat16* Kh  = Qh + 4096 * 512;
    __hip_bfloat16* cbh = Kh + 4096 * 512;
    __hip_bfloat16* WqT = cbh + 4096 * 512;          // 512*512
    __hip_bfloat16* WvT = WqT + 512 * 512;

    build_x_k<<<10240, 256, 0, stream>>>(z, X, Xh);
    cast_bf16_k<<<8192, 256, 0, stream>>>(cbk, cbh);
    transpose_cast_k<<<dim3(16, 16), 256, 0, stream>>>(Wq, WqT);
    transpose_cast_k<<<dim3(16, 16), 256, 0, stream>>>(Wv, WvT);
    pool_c_k<<<160, 256, 0, stream>>>(X, Wp, bp, Cp);
    // K projection + rmsnorm -> Kn fp32 + Kh bf16
    sgemm64_norm_k<<<dim3(64, 8), 256, 0, stream>>>(cbk, Wk, bk, gk, nullptr, Kn, Kh);
    // pooled Q projection + rmsnorm + c-fold -> Qpool fp32
    sgemm64_norm_k<<<dim3(16, 8), 256, 0, stream>>>(X + 4096 * 512, Wq, bq, gq,
                                                    Cp + 4096 * 8, Qpool, nullptr);
    // full-res Q projection (bf16 MFMA) + rmsnorm + c-fold -> Qh bf16
    bgemm_qnorm_k<<<dim3(32, 4), 256, 0, stream>>>(Xh, WqT, bq, gq, Cp, Qh);
    // V projection (bf16 MFMA) -> Vb fp32
    bgemm_bias_k<<<dim3(32, 4), 256, 0, stream>>>(cbh, WvT, bv, Vb);
    // full-res logits + argmax (bf16 MFMA)
    logits_full_k<<<dim3(32, 32), 256, 0, stream>>>(Qh, Kh, segval, segidx);
    // pooled logits + argmax (fp32, exact)
    logits_pool_k<<<dim3(16, 32), 256, 0, stream>>>(Qpool, Kn, segval, segidx);
    merge_code_k<<<20, 256, 0, stream>>>(segval, segidx, code);
    zero_counts_k<<<16, 256, 0, stream>>>(counts);
    hist_k<<<16, 256, 0, stream>>>(code, counts);
    perplexity_k<<<1, 256, 0, stream>>>(counts, out + 4 * 512 * 1024);
    zhat_k<<<8192, 256, 0, stream>>>(Vb, code, out);
}

// Round 3
// 323.683 us; speedup vs baseline: 2.0031x; 1.0616x over previous
//
#include <hip/hip_runtime.h>
#include <hip/hip_bf16.h>
#include <cfloat>
#include <math.h>

#define NFULL 4096
#define NPOOL 1024
#define NTOK  5120
#define VDIM  4096

typedef __attribute__((ext_vector_type(8))) short short8;   // 8 bf16 (4 VGPR)
typedef __attribute__((ext_vector_type(4))) float f4;       // MFMA acc
typedef unsigned long long u64;

#define MFMA16(a,b,c) __builtin_amdgcn_mfma_f32_16x16x32_bf16((a),(b),(c),0,0,0)

static __device__ __forceinline__ void gl_lds16(const void* g, void* l) {
    __builtin_amdgcn_global_load_lds(
        (const __attribute__((address_space(1))) unsigned int*)g,
        (__attribute__((address_space(3))) unsigned int*)l, 16, 0, 0);
}

// ---------------- build token matrix X (NTOK x 512), LDS-transposed --------
// full rows: X[b*1024+t][c] = z[b][c][t] (+bf16 Xh); pooled rows: mean4 over t
__global__ void build_x_k(const float* __restrict__ z, float* __restrict__ X,
                          __hip_bfloat16* __restrict__ Xh) {
    __shared__ float tile[32][33];
    int b = blockIdx.z, c0 = blockIdx.y * 32, t0 = blockIdx.x * 32;
    int tx = threadIdx.x & 31, ty = threadIdx.x >> 5;   // ty 0..7
    #pragma unroll
    for (int i = 0; i < 4; ++i) {
        int c = ty + i * 8;
        tile[c][tx] = z[((b << 9) + c0 + c) * 1024 + t0 + tx];
    }
    __syncthreads();
    #pragma unroll
    for (int i = 0; i < 4; ++i) {
        int tl = ty + i * 8;
        float v = tile[tx][tl];
        int tok = (b << 10) + t0 + tl;
        X[tok * 512 + c0 + tx] = v;
        Xh[tok * 512 + c0 + tx] = __float2bfloat16(v);
    }
    float m = 0.25f * (tile[tx][ty * 4] + tile[tx][ty * 4 + 1] +
                       tile[tx][ty * 4 + 2] + tile[tx][ty * 4 + 3]);
    int tq = (t0 >> 2) + ty;
    X[(NFULL + (b << 8) + tq) * 512 + c0 + tx] = m;
}

__global__ void cast_bf16_k(const float* __restrict__ s, __hip_bfloat16* __restrict__ d) {
    int i = blockIdx.x * 256 + threadIdx.x;
    d[i] = __float2bfloat16(s[i]);
}

// ---------------- transpose+cast 512x512 (z selects Wq->WqT / Wv->WvT) -----
__global__ void transpose_cast_k(const float* __restrict__ Wq, const float* __restrict__ Wv,
                                 __hip_bfloat16* __restrict__ WqT, __hip_bfloat16* __restrict__ WvT) {
    const float* W = blockIdx.z ? Wv : Wq;
    __hip_bfloat16* WT = blockIdx.z ? WvT : WqT;
    __shared__ float t[32][33];
    int bk = blockIdx.x * 32, bn = blockIdx.y * 32;
    int lx = threadIdx.x & 31, ly = threadIdx.x >> 5;
    #pragma unroll
    for (int i = 0; i < 4; ++i) {
        int r = ly * 4 + i;
        t[r][lx] = W[(bk + r) * 512 + bn + lx];
    }
    __syncthreads();
    #pragma unroll
    for (int i = 0; i < 4; ++i) {
        int r = ly * 4 + i;
        WT[(bn + r) * 512 + bk + lx] = __float2bfloat16(t[lx][r]);
    }
}

// ---------------- head-pool weights: Cp[NTOK x 8] = X @ Wp + bp ------------
__global__ void pool_c_k(const float* __restrict__ X, const float* __restrict__ Wp,
                         const float* __restrict__ bp, float* __restrict__ Cp) {
    __shared__ float W[4096];
    for (int i = threadIdx.x; i < 4096; i += 256) W[i] = Wp[i];
    __syncthreads();
    int tokBase = blockIdx.x * 32;
    int tl = threadIdx.x >> 3, h = threadIdx.x & 7;
    const float* x = X + (tokBase + tl) * 512;
    float s = 0.f;
    for (int k4 = 0; k4 < 128; ++k4) {
        float4 xv = *(const float4*)(x + k4 * 4);
        s = fmaf(xv.x, W[(k4 * 4 + 0) * 8 + h], s);
        s = fmaf(xv.y, W[(k4 * 4 + 1) * 8 + h], s);
        s = fmaf(xv.z, W[(k4 * 4 + 2) * 8 + h], s);
        s = fmaf(xv.w, W[(k4 * 4 + 3) * 8 + h], s);
    }
    Cp[(tokBase + tl) * 8 + h] = s + bp[h];
}

// ---------------- fp32 projection GEMM, split-K x2, virtual M --------------
// rows 0..4095: codebook@Wk ; rows 4096..5119: Xpool@Wq. Partials -> P0/P1.
__global__ __launch_bounds__(256) void proj_split_k(
    const float* __restrict__ cbk, const float* __restrict__ Xp,
    const float* __restrict__ Wk, const float* __restrict__ Wq,
    float* __restrict__ P0, float* __restrict__ P1) {
    __shared__ float As[16][68];
    __shared__ float Bs[16][68];
    int tid = threadIdx.x;
    int mB = blockIdx.x * 64;
    int nB = blockIdx.y * 64;
    int kOff = blockIdx.z * 256;
    const float* A; const float* B;
    if (mB < NFULL) { A = cbk + mB * 512; B = Wk; }
    else            { A = Xp + (mB - NFULL) * 512; B = Wq; }
    int ty = tid >> 4, tx = tid & 15;
    int arow = tid >> 2, achk = tid & 3;
    const float* Ap = A + arow * 512 + kOff + achk * 4;
    const float* Bp = B + (kOff + ty) * 512 + nB + tx * 4;
    float acc[4][4] = {};
    for (int kt = 0; kt < 16; ++kt) {
        float4 a = *(const float4*)(Ap + kt * 16);
        float4 b = *(const float4*)(Bp + kt * 16 * 512);
        __syncthreads();
        As[achk * 4 + 0][arow] = a.x; As[achk * 4 + 1][arow] = a.y;
        As[achk * 4 + 2][arow] = a.z; As[achk * 4 + 3][arow] = a.w;
        *(float4*)&Bs[ty][tx * 4] = b;
        __syncthreads();
        #pragma unroll
        for (int kk = 0; kk < 16; ++kk) {
            float4 av = *(const float4*)&As[kk][ty * 4];
            float4 bv = *(const float4*)&Bs[kk][tx * 4];
            float a4[4] = {av.x, av.y, av.z, av.w};
            float b4[4] = {bv.x, bv.y, bv.z, bv.w};
            #pragma unroll
            for (int i = 0; i < 4; ++i)
                #pragma unroll
                for (int j = 0; j < 4; ++j)
                    acc[i][j] = fmaf(a4[i], b4[j], acc[i][j]);
        }
    }
    float* P = blockIdx.z ? P1 : P0;
    #pragma unroll
    for (int i = 0; i < 4; ++i) {
        float4 r; r.x = acc[i][0]; r.y = acc[i][1]; r.z = acc[i][2]; r.w = acc[i][3];
        *(float4*)&P[(mB + ty * 4 + i) * 512 + nB + tx * 4] = r;
    }
}

// ---------------- finish: P0+P1+bias -> rmsnorm -> Kn/Kh/Qpool/Qh, Kmax ----
__global__ void norm_finish_k(const float* __restrict__ P0, const float* __restrict__ P1,
                              const float* __restrict__ bk, const float* __restrict__ bq,
                              const float* __restrict__ gk, const float* __restrict__ gq,
                              const float* __restrict__ Cp,
                              float* __restrict__ Kn, __hip_bfloat16* __restrict__ Kh,
                              float* __restrict__ Qpool, __hip_bfloat16* __restrict__ Qh,
                              unsigned int* __restrict__ Kmax2i) {
    int row = blockIdx.x;              // 0..5119
    int t = threadIdx.x;               // cols t and t+256
    bool isQ = row >= NFULL;
    const float* bias = isQ ? bq : bk;
    const float* g = isQ ? gq : gk;
    float v0 = P0[row * 512 + t] + P1[row * 512 + t] + bias[t];
    float v1 = P0[row * 512 + t + 256] + P1[row * 512 + t + 256] + bias[t + 256];
    float s0 = v0 * v0, s1 = v1 * v1;
    #pragma unroll
    for (int o = 32; o > 0; o >>= 1) { s0 += __shfl_xor(s0, o); s1 += __shfl_xor(s1, o); }
    float gd = g[t & 63];
    float o0 = v0 * rsqrtf(s0 * (1.0f / 64.0f) + 1e-5f) * gd;
    float o1 = v1 * rsqrtf(s1 * (1.0f / 64.0f) + 1e-5f) * gd;
    if (isQ) {
        float c0f = Cp[row * 8 + (t >> 6)] * 0.04419417382415922f;       // 1/(8*sqrt8)
        float c1f = Cp[row * 8 + 4 + (t >> 6)] * 0.04419417382415922f;
        o0 *= c0f; o1 *= c1f;
        Qpool[(row - NFULL) * 512 + t] = o0;
        Qpool[(row - NFULL) * 512 + t + 256] = o1;
        Qh[row * 512 + t] = __float2bfloat16(o0);
        Qh[row * 512 + t + 256] = __float2bfloat16(o1);
    } else {
        Kn[row * 512 + t] = o0;       Kn[row * 512 + t + 256] = o1;
        Kh[row * 512 + t] = __float2bfloat16(o0);
        Kh[row * 512 + t + 256] = __float2bfloat16(o1);
        float rs = o0 * o0 + o1 * o1;
        #pragma unroll
        for (int o = 32; o > 0; o >>= 1) rs += __shfl_xor(rs, o);
        __shared__ float wsum[4];
        if ((t & 63) == 0) wsum[t >> 6] = rs;
        __syncthreads();
        if (t == 0) {
            float tot = wsum[0] + wsum[1] + wsum[2] + wsum[3];
            atomicMax(Kmax2i, __float_as_uint(tot));   // positive floats: uint-monotone
        }
    }
}

// ---------------- bf16 MFMA 128x128 core, global_load_lds, 2-barrier -------
#define BGEMM2_PROLOG(AM, Bt)                                                  \
    __shared__ __hip_bfloat16 As[128 * 32];                                    \
    __shared__ __hip_bfloat16 Bs[128 * 32];                                    \
    int tid = threadIdx.x;                                                     \
    int mB = blockIdx.x * 128, nB = blockIdx.y * 128;                          \
    int lane = tid & 63, w = tid >> 6, wy = w >> 1, wx = w & 1;                \
    int lm = lane & 15, quad = lane >> 4;                                      \
    int r0 = tid >> 2, c0e = (tid & 3) * 8;                                    \
    const __hip_bfloat16* Ag0 = (AM) + (mB + r0) * 512 + c0e;                  \
    const __hip_bfloat16* Ag1 = (AM) + (mB + 64 + r0) * 512 + c0e;             \
    const __hip_bfloat16* Bg0 = (Bt) + (nB + r0) * 512 + c0e;                  \
    const __hip_bfloat16* Bg1 = (Bt) + (nB + 64 + r0) * 512 + c0e;             \
    __hip_bfloat16* Al = As + tid * 8;                                         \
    __hip_bfloat16* Bl = Bs + tid * 8;                                         \
    f4 acc[4][4];                                                              \
    _Pragma("unroll") for (int i = 0; i < 4; ++i)                              \
        _Pragma("unroll") for (int j = 0; j < 4; ++j)                          \
            acc[i][j] = f4{0.f, 0.f, 0.f, 0.f};                                \
    for (int kt = 0; kt < 16; ++kt) {                                          \
        __syncthreads();                                                       \
        gl_lds16(Ag0 + kt * 32, Al);                                           \
        gl_lds16(Ag1 + kt * 32, Al + 2048);                                    \
        gl_lds16(Bg0 + kt * 32, Bl);                                           \
        gl_lds16(Bg1 + kt * 32, Bl + 2048);                                    \
        __syncthreads();                                                       \
        short8 aF[4], bF[4];                                                   \
        _Pragma("unroll") for (int mt = 0; mt < 4; ++mt)                       \
            aF[mt] = *(const short8*)(As + (wy * 64 + mt * 16 + lm) * 32 + quad * 8); \
        _Pragma("unroll") for (int nt = 0; nt < 4; ++nt)                       \
            bF[nt] = *(const short8*)(Bs + (wx * 64 + nt * 16 + lm) * 32 + quad * 8); \
        _Pragma("unroll") for (int mt = 0; mt < 4; ++mt)                       \
            _Pragma("unroll") for (int nt = 0; nt < 4; ++nt)                   \
                acc[mt][nt] = MFMA16(aF[mt], bF[nt], acc[mt][nt]);             \
    }

// V projection: fp32 out = A@Bt^T + bias
__global__ __launch_bounds__(256) void bgemm_bias_k(
    const __hip_bfloat16* __restrict__ AM, const __hip_bfloat16* __restrict__ Bt,
    const float* __restrict__ bias, float* __restrict__ C) {
    BGEMM2_PROLOG(AM, Bt)
    float bb[4];
    #pragma unroll
    for (int nt = 0; nt < 4; ++nt) bb[nt] = bias[nB + wx * 64 + nt * 16 + lm];
    #pragma unroll
    for (int mt = 0; mt < 4; ++mt)
        #pragma unroll
        for (int reg = 0; reg < 4; ++reg) {
            int m = mB + wy * 64 + mt * 16 + quad * 4 + reg;
            #pragma unroll
            for (int nt = 0; nt < 4; ++nt)
                C[m * 512 + nB + wx * 64 + nt * 16 + lm] = acc[mt][nt][reg] + bb[nt];
        }
}

// full-res Q projection + fused rmsnorm + c-fold -> bf16
__global__ __launch_bounds__(256) void bgemm_qnorm_k(
    const __hip_bfloat16* __restrict__ AM, const __hip_bfloat16* __restrict__ Bt,
    const float* __restrict__ bias, const float* __restrict__ gq,
    const float* __restrict__ cp, __hip_bfloat16* __restrict__ outH) {
    BGEMM2_PROLOG(AM, Bt)
    int h = blockIdx.y * 2 + wx;
    float bb[4], gg[4];
    #pragma unroll
    for (int nt = 0; nt < 4; ++nt) {
        bb[nt] = bias[h * 64 + nt * 16 + lm];
        gg[nt] = gq[nt * 16 + lm];
    }
    #pragma unroll
    for (int mt = 0; mt < 4; ++mt)
        #pragma unroll
        for (int reg = 0; reg < 4; ++reg) {
            int tok = mB + wy * 64 + mt * 16 + quad * 4 + reg;
            float vv[4], ss = 0.f;
            #pragma unroll
            for (int nt = 0; nt < 4; ++nt) { vv[nt] = acc[mt][nt][reg] + bb[nt]; ss = fmaf(vv[nt], vv[nt], ss); }
            #pragma unroll
            for (int off = 1; off < 16; off <<= 1) ss += __shfl_xor(ss, off);
            float sc = rsqrtf(ss * (1.0f / 64.0f) + 1e-5f) * cp[tok * 8 + h] * 0.04419417382415922f;
            #pragma unroll
            for (int nt = 0; nt < 4; ++nt)
                outH[tok * 512 + h * 64 + nt * 16 + lm] = __float2bfloat16(vv[nt] * sc * gg[nt]);
        }
}

// logits over all 5120 tokens. Full rows -> packed atomic argmax;
// pooled rows -> full bf16 logit row (for candidate rescore).
__global__ __launch_bounds__(256) void logits_full_k(
    const __hip_bfloat16* __restrict__ AM, const __hip_bfloat16* __restrict__ Bt,
    u64* __restrict__ packed, __hip_bfloat16* __restrict__ Lp) {
    BGEMM2_PROLOG(AM, Bt)
    if (blockIdx.x < 32) {
        #pragma unroll
        for (int mt = 0; mt < 4; ++mt)
            #pragma unroll
            for (int reg = 0; reg < 4; ++reg) {
                float bv = -FLT_MAX; int bi = 0;
                #pragma unroll
                for (int nt = 0; nt < 4; ++nt) {
                    float v = acc[mt][nt][reg];
                    int n = nB + wx * 64 + nt * 16 + lm;
                    if (v > bv) { bv = v; bi = n; }
                }
                #pragma unroll
                for (int off = 1; off < 16; off <<= 1) {
                    float ov = __shfl_xor(bv, off);
                    int oi = __shfl_xor(bi, off);
                    if (ov > bv || (ov == bv && oi < bi)) { bv = ov; bi = oi; }
                }
                if (lm == 0) {
                    unsigned ub = __float_as_uint(bv);
                    ub = (ub & 0x80000000u) ? ~ub : (ub | 0x80000000u);
                    u64 key = ((u64)ub << 32) | (u64)(0xFFFFFFFFu - (unsigned)bi);
                    int tok = mB + wy * 64 + mt * 16 + quad * 4 + reg;
                    atomicMax(&packed[tok], key);
                }
            }
    } else {
        #pragma unroll
        for (int mt = 0; mt < 4; ++mt)
            #pragma unroll
            for (int reg = 0; reg < 4; ++reg) {
                int tok = mB + wy * 64 + mt * 16 + quad * 4 + reg;
                long long base = (long long)(tok - NFULL) * 4096;
                #pragma unroll
                for (int nt = 0; nt < 4; ++nt)
                    Lp[base + nB + wx * 64 + nt * 16 + lm] =
                        __float2bfloat16(acc[mt][nt][reg]);
            }
    }
}

// ---------------- exact rescore of pooled tokens ---------------------------
// candidate = bf16 logit >= bf16max - delta, delta = 2^-7 * ||q|| * max||k||
// (rigorous bound on bf16 round + MFMA + store-round error). Exact fp32 dot
// per candidate, ascending n, strict > => np.argmax first-index semantics.
__global__ void rescore_k(const float* __restrict__ Qpool, const float* __restrict__ Kn,
                          const __hip_bfloat16* __restrict__ Lp,
                          const unsigned int* __restrict__ Kmax2i,
                          int* __restrict__ codeP) {
    int wid = threadIdx.x >> 6, lane = threadIdx.x & 63;
    int tok = blockIdx.x * 4 + wid;          // 0..1023
    const float* q = Qpool + tok * 512;
    float4 q0 = *(const float4*)(q + lane * 8);
    float4 q1 = *(const float4*)(q + lane * 8 + 4);
    float qs = q0.x * q0.x + q0.y * q0.y + q0.z * q0.z + q0.w * q0.w +
               q1.x * q1.x + q1.y * q1.y + q1.z * q1.z + q1.w * q1.w;
    #pragma unroll
    for (int o = 32; o > 0; o >>= 1) qs += __shfl_xor(qs, o);
    float delta = 0.0078125f * sqrtf(qs) * sqrtf(__uint_as_float(*Kmax2i));
    const __hip_bfloat16* row = Lp + (long long)tok * 4096;
    float mx = -FLT_MAX;
    for (int c = 0; c < 64; ++c)
        mx = fmaxf(mx, __bfloat162float(row[c * 64 + lane]));
    #pragma unroll
    for (int o = 32; o > 0; o >>= 1) mx = fmaxf(mx, __shfl_xor(mx, o));
    float thr = mx - delta;
    float bv = -FLT_MAX; int bi = 0;
    for (int c = 0; c < 64; ++c) {
        float v = __bfloat162float(row[c * 64 + lane]);
        u64 mask = __ballot(v >= thr);
        while (mask) {
            int l = __ffsll((long long)mask) - 1;
            mask &= mask - 1;
            int n = c * 64 + l;
            const float* k = Kn + n * 512;
            float4 k0 = *(const float4*)(k + lane * 8);
            float4 k1 = *(const float4*)(k + lane * 8 + 4);
            float d = q0.x * k0.x;
            d = fmaf(q0.y, k0.y, d); d = fmaf(q0.z, k0.z, d); d = fmaf(q0.w, k0.w, d);
            d = fmaf(q1.x, k1.x, d); d = fmaf(q1.y, k1.y, d);
            d = fmaf(q1.z, k1.z, d); d = fmaf(q1.w, k1.w, d);
            #pragma unroll
            for (int o = 32; o > 0; o >>= 1) d += __shfl_xor(d, o);
            if (d > bv) { bv = d; bi = n; }   // ascending n => first max wins
        }
    }
    if (lane == 0) codeP[tok] = bi;
}

// ---------------- histogram (full tokens, from packed) + perplexity --------
__global__ void merge_hist_k(const u64* __restrict__ packed, int* __restrict__ counts) {
    int tok = blockIdx.x * 256 + threadIdx.x;
    if (tok < NFULL) {
        int bi = (int)(0xFFFFFFFFu - (unsigned)(packed[tok] & 0xFFFFFFFFu));
        atomicAdd(&counts[bi], 1);
    }
}

__global__ void perplexity_k(const int* __restrict__ counts, float* __restrict__ out) {
    __shared__ float red[256];
    float s = 0.f;
    for (int i = threadIdx.x; i < VDIM; i += 256) {
        float p = (float)counts[i] * (1.0f / 4096.0f);
        s += p * logf(p + 1e-7f);
    }
    red[threadIdx.x] = s; __syncthreads();
    for (int st = 128; st > 0; st >>= 1) {
        if (threadIdx.x < st) red[threadIdx.x] += red[threadIdx.x + st];
        __syncthreads();
    }
    if (threadIdx.x == 0) out[0] = expf(-red[0]);
}

// ---------------- z_hat: gather value rows + linear interp x4 ---------------
__global__ void zhat_k(const float* __restrict__ Vv, const int* __restrict__ codeP,
                       float* __restrict__ out) {
    int idx = blockIdx.x * 256 + threadIdx.x;   // 4*512*1024
    int t = idx & 1023;
    int bc = idx >> 10;
    int b = bc >> 9, c = bc & 511;
    float pos = (t + 0.5f) * 0.25f - 0.5f;
    pos = fminf(fmaxf(pos, 0.0f), 255.0f);
    float fi = floorf(pos);
    int i0 = (int)fi;
    int i1 = min(i0 + 1, 255);
    float wgt = pos - fi;
    const int* cp = codeP + (b << 8);
    float v0 = Vv[cp[i0] * 512 + c];
    float v1 = Vv[cp[i1] * 512 + c];
    out[idx] = v0 * (1.0f - wgt) + v1 * wgt;
}

extern "C" void kernel_launch(void* const* d_in, const int* in_sizes, int n_in,
                              void* d_out, int out_size, void* d_ws, size_t ws_size,
                              hipStream_t stream) {
    const float* z   = (const float*)d_in[0];
    const float* cbk = (const float*)d_in[2];
    const float* Wq  = (const float*)d_in[3];
    const float* bq  = (const float*)d_in[4];
    const float* Wk  = (const float*)d_in[5];
    const float* bk  = (const float*)d_in[6];
    const float* Wv  = (const float*)d_in[7];
    const float* bv  = (const float*)d_in[8];
    const float* Wp  = (const float*)d_in[9];
    const float* bp  = (const float*)d_in[10];
    const float* gq  = (const float*)d_in[11];
    const float* gk  = (const float*)d_in[12];
    float* out = (float*)d_out;

    // ---- workspace layout (~69.4 MB) ----
    float* X      = (float*)d_ws;            // 5120*512
    float* Qpool  = X + 5120 * 512;          // 1024*512
    float* Kn     = Qpool + 1024 * 512;      // 4096*512
    float* Vb     = Kn + 4096 * 512;         // 4096*512
    float* Cp     = Vb + 4096 * 512;         // 5120*8
    float* P0     = Cp + 5120 * 8;           // 5120*512 (later aliased by Lp)
    float* P1     = P0 + 5120 * 512;         // 5120*512
    u64*   packed = (u64*)(P1 + 5120 * 512); // 4096
    int*   counts = (int*)(packed + 4096);   // 4096
    unsigned int* Kmax2i = (unsigned int*)(counts + 4096);  // 4 (padded)
    int*   codeP  = (int*)(Kmax2i + 4);      // 1024
    __hip_bfloat16* Qh  = (__hip_bfloat16*)(codeP + 1024);  // 5120*512
    __hip_bfloat16* Kh  = Qh + 5120 * 512;   // 4096*512
    __hip_bfloat16* Xh  = Kh + 4096 * 512;   // 4096*512
    __hip_bfloat16* cbh = Xh + 4096 * 512;   // 4096*512
    __hip_bfloat16* WqT = cbh + 4096 * 512;  // 512*512
    __hip_bfloat16* WvT = WqT + 512 * 512;   // 512*512
    __hip_bfloat16* Lp  = (__hip_bfloat16*)P0;  // alias: 1024*4096 bf16 (8 MB <= 10.5 MB)

    // zero packed + counts + Kmax2 in one shot
    hipMemsetAsync(packed, 0, 4096 * 8 + 4096 * 4 + 16, stream);

    build_x_k<<<dim3(32, 16, 4), 256, 0, stream>>>(z, X, Xh);
    cast_bf16_k<<<8192, 256, 0, stream>>>(cbk, cbh);
    transpose_cast_k<<<dim3(16, 16, 2), 256, 0, stream>>>(Wq, Wv, WqT, WvT);
    pool_c_k<<<160, 256, 0, stream>>>(X, Wp, bp, Cp);
    proj_split_k<<<dim3(80, 8, 2), 256, 0, stream>>>(cbk, X + 4096 * 512, Wk, Wq, P0, P1);
    norm_finish_k<<<5120, 256, 0, stream>>>(P0, P1, bk, bq, gk, gq, Cp,
                                            Kn, Kh, Qpool, Qh, Kmax2i);
    bgemm_qnorm_k<<<dim3(32, 4), 256, 0, stream>>>(Xh, WqT, bq, gq, Cp, Qh);
    bgemm_bias_k<<<dim3(32, 4), 256, 0, stream>>>(cbh, WvT, bv, Vb);
    logits_full_k<<<dim3(40, 32), 256, 0, stream>>>(Qh, Kh, packed, Lp);
    rescore_k<<<256, 256, 0, stream>>>(Qpool, Kn, Lp, Kmax2i, codeP);
    merge_hist_k<<<16, 256, 0, stream>>>(packed, counts);
    perplexity_k<<<1, 256, 0, stream>>>(counts, out + 4 * 512 * 1024);
    zhat_k<<<8192, 256, 0, stream>>>(Vb, codeP, out);
}